// Round 4
// baseline (259.133 us; speedup 1.0000x reference)
//
#include <hip/hip_runtime.h>
#include <hip/hip_bf16.h>
#include <math.h>

typedef __attribute__((ext_vector_type(8))) short bf16x8;
typedef __attribute__((ext_vector_type(4))) float f32x4;

static __device__ inline ushort f2bf(float f) {
    union { float f; unsigned u; } v; v.f = f;
    unsigned r = (v.u + 0x7fff + ((v.u >> 16) & 1)) >> 16;   // RNE
    return (ushort)r;
}

#define GLD_LDS(g, l) \
    __builtin_amdgcn_global_load_lds( \
        (const __attribute__((address_space(1))) void*)(g), \
        (__attribute__((address_space(3))) void*)(l), 16, 0, 0)

// ---------------------------------------------------------------------------
// x fp32 -> bf16
// ---------------------------------------------------------------------------
__global__ __launch_bounds__(256) void convert_x(
    const float* __restrict__ x, ushort* __restrict__ xb)
{
    const size_t i = ((size_t)blockIdx.x * 256 + threadIdx.x) * 8;
    float4 a = *(const float4*)(x + i);
    float4 b = *(const float4*)(x + i + 4);
    bf16x8 t;
    t[0] = (short)f2bf(a.x); t[1] = (short)f2bf(a.y);
    t[2] = (short)f2bf(a.z); t[3] = (short)f2bf(a.w);
    t[4] = (short)f2bf(b.x); t[5] = (short)f2bf(b.y);
    t[6] = (short)f2bf(b.z); t[7] = (short)f2bf(b.w);
    *(bf16x8*)(xb + i) = t;
}

// ---------------------------------------------------------------------------
// Weights fp32 [K][N] -> Wt bf16 [4096][1024] transposed
// ---------------------------------------------------------------------------
__global__ __launch_bounds__(256) void prep_w(
    const float* __restrict__ Wq, const float* __restrict__ Wkv,
    const float* __restrict__ Wo, ushort* __restrict__ Wt)
{
    const int w = threadIdx.x >> 6;
    const int lane = threadIdx.x & 63;
    const int tile = blockIdx.x * 4 + w;
    const int r0 = (tile >> 4) << 6;
    const int k0 = (tile & 15) << 6;

    const float* src; int ld, c0;
    if (r0 < 1024)      { src = Wq;  ld = 1024; c0 = r0; }
    else if (r0 < 3072) { src = Wkv; ld = 2048; c0 = r0 - 1024; }
    else                { src = Wo;  ld = 1024; c0 = r0 - 3072; }

    ushort v[64];
    #pragma unroll
    for (int k = 0; k < 64; ++k)
        v[k] = f2bf(src[(size_t)(k0 + k) * ld + c0 + lane]);

    ushort* dst = Wt + (size_t)(r0 + lane) * 1024 + k0;
    #pragma unroll
    for (int k = 0; k < 64; k += 8) {
        bf16x8 t;
        #pragma unroll
        for (int j = 0; j < 8; ++j) t[j] = (short)v[k + j];
        *(bf16x8*)(dst + k) = t;
    }
}

// ---------------------------------------------------------------------------
// Occupancy-first counted-vmcnt GEMM: tile 128(M)x256(N), BK=32, 512 thr,
// 8 waves (2Mx4N, per-wave 64x64 = acc[4][4]). TRIPLE-buffered LDS (72 KB ->
// 2 blocks/CU = 16 waves: cross-block TLP hides drains, m114 mechanism).
// Per K-step: stage tile u+2 into the buffer last read at step u-1 (WAR-safe:
// its readers drained before the end-of-step-(u-1) barrier, which precedes
// this issue); read buf u%3 (compiler emits fine-grained lgkmcnt); 16 MFMA;
// vmcnt(3) (tile u+1's 3 loads landed, u+2's 3 stay in flight); one barrier.
// LDS reads conflict-free (2-way = free): chunk ^= (row>>1)&3 swizzle applied
// on the GLOBAL source (global_load_lds writes linearly), same on read side.
// ---------------------------------------------------------------------------
#define STG32(t, Ad, Bd) { \
    GLD_LDS(aS + (size_t)(t) * 32, (Ad) + ldst); \
    GLD_LDS(bSlo + (size_t)(t) * 32, (Bd) + ldst); \
    GLD_LDS(bShi + (size_t)(t) * 32, (Bd) + 128 * 32 + ldst); }

#define GEMM_PIPE(Aptr, Btptr, NXT, NWG)                                       \
    __shared__ ushort As[3][128 * 32];                                         \
    __shared__ ushort Bs[3][256 * 32];                                         \
    const int tid = threadIdx.x;                                               \
    const int lane = tid & 63;                                                 \
    const int w = tid >> 6;                                                    \
    const int l15 = lane & 15;                                                 \
    const int quad = lane >> 4;                                                \
    const int wm = w >> 2, wn = w & 3;                                         \
    const int lin = blockIdx.y * (NXT) + blockIdx.x;                           \
    const int wg = (lin & 7) * ((NWG) >> 3) + (lin >> 3);                      \
    const int rowBase = (wg / (NXT)) * 128;                                    \
    const int colBase = (wg % (NXT)) * 256;                                    \
    /* staging: rows of 32 bf16 = 64B = 4 chunks of 16B */                     \
    const int sr = tid >> 2, sc = tid & 3;                                     \
    const int ldst = sr * 32 + sc * 8;                                         \
    const int gsw = (sc ^ ((sr >> 1) & 3)) << 3;                               \
    const ushort* aS   = (Aptr)  + (size_t)(rowBase + sr) * 1024 + gsw;        \
    const ushort* bSlo = (Btptr) + (size_t)(colBase + sr) * 1024 + gsw;        \
    const ushort* bShi = bSlo + (size_t)128 * 1024;                            \
    /* read side: same involution, rows within a frag group share (l15>>1)&3 */\
    const int co = ((quad ^ ((l15 >> 1) & 3)) << 3);                           \
    f32x4 acc[4][4];                                                           \
    _Pragma("unroll")                                                          \
    for (int i_ = 0; i_ < 4; ++i_)                                             \
        _Pragma("unroll")                                                      \
        for (int j_ = 0; j_ < 4; ++j_) acc[i_][j_] = (f32x4){0.f, 0.f, 0.f, 0.f}; \
    ushort *Acur = As[0], *Anxt = As[1], *Apre = As[2];                        \
    ushort *Bcur = Bs[0], *Bnxt = Bs[1], *Bpre = Bs[2];                        \
    STG32(0, Acur, Bcur)                                                       \
    STG32(1, Anxt, Bnxt)                                                       \
    asm volatile("s_waitcnt vmcnt(3)" ::: "memory");                           \
    __builtin_amdgcn_s_barrier();                                              \
    asm volatile("" ::: "memory");                                             \
    _Pragma("unroll 1")                                                        \
    for (int u = 0; u < 32; ++u) {                                             \
        if (u + 2 < 32) { STG32(u + 2, Apre, Bpre) }                           \
        const ushort* aC = Acur + (wm * 64 + l15) * 32;                        \
        const ushort* bC = Bcur + (wn * 64 + l15) * 32;                        \
        bf16x8 aF[4], bF[4];                                                   \
        _Pragma("unroll")                                                      \
        for (int ni = 0; ni < 4; ++ni)                                         \
            bF[ni] = *(const bf16x8*)(bC + ni * 512 + co);                     \
        _Pragma("unroll")                                                      \
        for (int mi = 0; mi < 4; ++mi)                                         \
            aF[mi] = *(const bf16x8*)(aC + mi * 512 + co);                     \
        __builtin_amdgcn_s_setprio(1);                                         \
        _Pragma("unroll")                                                      \
        for (int mi = 0; mi < 4; ++mi)                                         \
            _Pragma("unroll")                                                  \
            for (int ni = 0; ni < 4; ++ni)                                     \
                acc[mi][ni] = __builtin_amdgcn_mfma_f32_16x16x32_bf16(         \
                    aF[mi], bF[ni], acc[mi][ni], 0, 0, 0);                     \
        __builtin_amdgcn_s_setprio(0);                                         \
        if (u < 30)       { asm volatile("s_waitcnt vmcnt(3)" ::: "memory"); } \
        else if (u == 30) { asm volatile("s_waitcnt vmcnt(0)" ::: "memory"); } \
        if (u < 31) {                                                          \
            __builtin_amdgcn_s_barrier();                                      \
            asm volatile("" ::: "memory");                                     \
        }                                                                      \
        ushort* tA = Acur; Acur = Anxt; Anxt = Apre; Apre = tA;                \
        ushort* tB = Bcur; Bcur = Bnxt; Bnxt = Bpre; Bpre = tB;                \
    }

// ---------------------------------------------------------------------------
// GEMM 1: xb x Wt[0:3072] -> Q (pre-scaled by 0.125*log2e), K in [bh][n][64];
//         V directly transposed into Vt [bh*64+d][2048]
// ---------------------------------------------------------------------------
__global__ __launch_bounds__(512, 4) void gemm_qkv(
    const ushort* __restrict__ A, const ushort* __restrict__ Bt,
    ushort* __restrict__ Qb, ushort* __restrict__ Kb, ushort* __restrict__ Vt)
{
    GEMM_PIPE(A, Bt, 12, 768)

    const int seg = colBase >> 10;          // 0=Q 1=K 2=V
    if (seg == 2) {
        #pragma unroll
        for (int mi = 0; mi < 4; ++mi) {
            #pragma unroll
            for (int ni = 0; ni < 4; ++ni) {
                const int c = (colBase + wn*64 + ni*16 + l15) & 1023;
                const int h = c >> 6, d = c & 63;
                const int m = rowBase + wm*64 + mi*16 + quad*4;
                const int b = m >> 11, nn = m & 2047;
                ushort4 v;
                v.x = f2bf(acc[mi][ni][0]); v.y = f2bf(acc[mi][ni][1]);
                v.z = f2bf(acc[mi][ni][2]); v.w = f2bf(acc[mi][ni][3]);
                *(ushort4*)(Vt + ((size_t)(b*16 + h)*64 + d)*2048 + nn) = v;
            }
        }
    } else {
        ushort* dst = seg ? Kb : Qb;
        // Q pre-scale: 1/sqrt(64) * log2(e)  (softmax runs in base-2 domain)
        const float sc2 = seg ? 1.0f : 0.18033688011112042f;
        #pragma unroll
        for (int mi = 0; mi < 4; ++mi) {
            #pragma unroll
            for (int ni = 0; ni < 4; ++ni) {
                const int c = (colBase + wn*64 + ni*16 + l15) & 1023;
                const int h = c >> 6, d = c & 63;
                #pragma unroll
                for (int r = 0; r < 4; ++r) {
                    const int m = rowBase + wm*64 + mi*16 + quad*4 + r;
                    const int b = m >> 11, nn = m & 2047;
                    dst[((((size_t)b*16 + h)*2048 + nn) << 6) + d] = f2bf(acc[mi][ni][r] * sc2);
                }
            }
        }
    }
}

// ---------------------------------------------------------------------------
// GEMM 2: Ob x Wt[3072:4096] + bo -> fp32 out
// ---------------------------------------------------------------------------
__global__ __launch_bounds__(512, 4) void gemm_out(
    const ushort* __restrict__ A, const ushort* __restrict__ Bt,
    const float* __restrict__ bo, float* __restrict__ out)
{
    GEMM_PIPE(A, Bt, 4, 256)

    #pragma unroll
    for (int mi = 0; mi < 4; ++mi) {
        #pragma unroll
        for (int ni = 0; ni < 4; ++ni) {
            const int n = colBase + wn*64 + ni*16 + l15;
            const float bb = bo[n];
            #pragma unroll
            for (int r = 0; r < 4; ++r) {
                const int m = rowBase + wm*64 + mi*16 + quad*4 + r;
                out[(size_t)m * 1024 + n] = acc[mi][ni][r] + bb;
            }
        }
    }
}

// ---------------------------------------------------------------------------
// Flash attention v5: unpaired q-tiles (grid 1024, qt-descending dispatch),
// double-buffered LDS K/V, S^T trick, skip-rescale on no-new-max.
// Block = 4 waves x 32 q-rows = one 128-row q-tile.
// ---------------------------------------------------------------------------
__device__ __forceinline__ bf16x8 lds_frag(const ushort* S, int row, int chunk) {
    return *(const bf16x8*)(S + row * 64 + ((chunk ^ (row & 7)) << 3));
}

__global__ __launch_bounds__(256, 2) void flash_mfma(
    const ushort* __restrict__ Qb,
    const ushort* __restrict__ Kb,
    const ushort* __restrict__ Vt,
    ushort* __restrict__ Ob)
{
    __shared__ ushort Ks[2][4096];
    __shared__ ushort Vs[2][4096];
    __shared__ ushort PsAll[4][32][72];

    const int tid = threadIdx.x;
    const int w = tid >> 6;
    const int lane = tid & 63;
    const int l15 = lane & 15;
    const int quad = lane >> 4;
    ushort (*Ps)[72] = PsAll[w];

    // 1024 blocks: [qt:4][bh_hi:3][xcd:3]; qt descending so long blocks first;
    // 8 heads per XCD slot (4MB K+V resident in one L2)
    const int blk = blockIdx.x;
    const int bh = ((blk & 7) << 3) | ((blk >> 3) & 7);
    const int qt = 15 - (blk >> 6);
    const int nt = 2 * qt + 2;
    const int rb0 = (qt << 7) + w * 32;

    // staging maps (xor-swizzled, 2x 16B chunks per thread per buffer)
    const int sr0 = tid >> 3, sr1 = sr0 + 32;
    const int cg0 = (tid & 7) ^ (sr0 & 7);
    const int cg1 = (tid & 7) ^ (sr1 & 7);
    const ushort* kgb = Kb + (size_t)bh * 131072;
    const ushort* vgb = Vt + (size_t)bh * 131072;

    // Q fragments (pre-scaled by 0.125*log2e)
    bf16x8 qf[2][2];
    #pragma unroll
    for (int mi = 0; mi < 2; ++mi) {
        const ushort* qp = Qb + ((size_t)bh * 2048 + rb0 + mi*16 + l15) * 64 + quad * 8;
        qf[mi][0] = *(const bf16x8*)qp;
        qf[mi][1] = *(const bf16x8*)(qp + 32);
    }

    bf16x8 bones;
    #pragma unroll
    for (int j = 0; j < 8; ++j) bones[j] = (short)0x3F80;   // bf16 1.0

    float m_r[2];
    f32x4 o[2][4], lacc[2];
    #pragma unroll
    for (int mi = 0; mi < 2; ++mi) {
        m_r[mi] = -INFINITY;
        lacc[mi] = (f32x4){0.f, 0.f, 0.f, 0.f};
        #pragma unroll
        for (int nb = 0; nb < 4; ++nb) o[mi][nb] = (f32x4){0.f, 0.f, 0.f, 0.f};
    }

    // prefetch tile 0 -> buf 0
    GLD_LDS(kgb + sr0*64 + cg0*8, &Ks[0][tid*8]);
    GLD_LDS(kgb + sr1*64 + cg1*8, &Ks[0][tid*8 + 2048]);
    GLD_LDS(vgb + (size_t)sr0*2048 + cg0*8, &Vs[0][tid*8]);
    GLD_LDS(vgb + (size_t)sr1*2048 + cg1*8, &Vs[0][tid*8 + 2048]);

    for (int t = 0; t < nt; ++t) {
        __syncthreads();                      // drains own GLDs; joins all waves
        const int cur = t & 1;
        if (t + 1 < nt) {
            const int jn = t + 1;
            ushort* kd = &Ks[cur ^ 1][tid * 8];
            ushort* vd = &Vs[cur ^ 1][tid * 8];
            GLD_LDS(kgb + (size_t)jn*4096 + sr0*64 + cg0*8, kd);
            GLD_LDS(kgb + (size_t)jn*4096 + sr1*64 + cg1*8, kd + 2048);
            GLD_LDS(vgb + (size_t)sr0*2048 + jn*64 + cg0*8, vd);
            GLD_LDS(vgb + (size_t)sr1*2048 + jn*64 + cg1*8, vd + 2048);
        }
        const int j0 = t << 6;
        if (j0 > rb0 + 31) continue;          // wave-uniform; barrier is at loop top

        const ushort* Ksb = Ks[cur];
        const ushort* Vsb = Vs[cur];

        // ---- S^T = K Q^T : [64 keys][32 qrows]; lane holds one qrow (l15) ----
        f32x4 St[2][4];                       // [mi][kb]
        #pragma unroll
        for (int kb = 0; kb < 4; ++kb) {
            bf16x8 ka = lds_frag(Ksb, kb*16 + l15, quad);
            bf16x8 kc = lds_frag(Ksb, kb*16 + l15, quad + 4);
            #pragma unroll
            for (int mi = 0; mi < 2; ++mi) {
                f32x4 s = (f32x4){0.f, 0.f, 0.f, 0.f};
                s = __builtin_amdgcn_mfma_f32_16x16x32_bf16(ka, qf[mi][0], s, 0, 0, 0);
                s = __builtin_amdgcn_mfma_f32_16x16x32_bf16(kc, qf[mi][1], s, 0, 0, 0);
                St[mi][kb] = s;
            }
        }

        #pragma unroll
        for (int mi = 0; mi < 2; ++mi) {
            const int qrow = rb0 + mi*16 + l15;
            if (j0 + 63 > rb0 + mi*16) {      // causal mask (straddling tiles only)
                #pragma unroll
                for (int kb = 0; kb < 4; ++kb) {
                    const int kbase = j0 + kb*16 + quad*4;
                    #pragma unroll
                    for (int r = 0; r < 4; ++r)
                        if (kbase + r > qrow) St[mi][kb][r] = -INFINITY;
                }
            }
            // lane-local max over this row's 16 scores + 2 cross-quad shuffles
            f32x4 mv = St[mi][0];
            #pragma unroll
            for (int kb = 1; kb < 4; ++kb)
                #pragma unroll
                for (int r = 0; r < 4; ++r) mv[r] = fmaxf(mv[r], St[mi][kb][r]);
            float mx = fmaxf(fmaxf(mv[0], mv[1]), fmaxf(mv[2], mv[3]));
            mx = fmaxf(mx, __shfl_xor(mx, 16));
            mx = fmaxf(mx, __shfl_xor(mx, 32));
            const float mold = m_r[mi];
            const float mnew = fmaxf(mold, mx);
            // skip-rescale: most tiles don't raise any row max
            if (__any(mnew > mold)) {
                m_r[mi] = mnew;
                const float corr = __builtin_amdgcn_exp2f(mold - mnew);
                // corr -> O-register layout (rows quad*4+r live in lanes 0..15)
                float ct[4];
                #pragma unroll
                for (int r = 0; r < 4; ++r) ct[r] = __shfl(corr, quad*4 + r);
                #pragma unroll
                for (int r = 0; r < 4; ++r) lacc[mi][r] *= ct[r];
                #pragma unroll
                for (int nb = 0; nb < 4; ++nb)
                    #pragma unroll
                    for (int r = 0; r < 4; ++r) o[mi][nb][r] *= ct[r];
            }
            // exp2 (base-2 domain) — mnew is a lane scalar for all 16 scores
            #pragma unroll
            for (int kb = 0; kb < 4; ++kb)
                #pragma unroll
                for (int r = 0; r < 4; ++r)
                    St[mi][kb][r] = __builtin_amdgcn_exp2f(St[mi][kb][r] - mnew);
            // pack 4 scores -> bf16x4, one ds_write_b64 per kb
            #pragma unroll
            for (int kb = 0; kb < 4; ++kb) {
                union { float f; unsigned u; } c0, c1, c2, c3;
                c0.f = St[mi][kb][0]; c1.f = St[mi][kb][1];
                c2.f = St[mi][kb][2]; c3.f = St[mi][kb][3];
                uint2 pk;
                pk.x = (c0.u >> 16) | (c1.u & 0xFFFF0000u);
                pk.y = (c2.u >> 16) | (c3.u & 0xFFFF0000u);
                *(uint2*)&Ps[mi*16 + l15][kb*16 + quad*4] = pk;
            }
        }

        // ---- O += P V ; l += P . 1 ----
        bf16x8 pf[2][2];
        #pragma unroll
        for (int mi = 0; mi < 2; ++mi) {
            pf[mi][0] = *(const bf16x8*)&Ps[mi*16 + l15][quad * 8];
            pf[mi][1] = *(const bf16x8*)&Ps[mi*16 + l15][32 + quad * 8];
        }
        #pragma unroll
        for (int mi = 0; mi < 2; ++mi) {
            lacc[mi] = __builtin_amdgcn_mfma_f32_16x16x32_bf16(pf[mi][0], bones, lacc[mi], 0, 0, 0);
            lacc[mi] = __builtin_amdgcn_mfma_f32_16x16x32_bf16(pf[mi][1], bones, lacc[mi], 0, 0, 0);
        }
        #pragma unroll
        for (int nb = 0; nb < 4; ++nb) {
            bf16x8 va = lds_frag(Vsb, nb*16 + l15, quad);
            bf16x8 vc = lds_frag(Vsb, nb*16 + l15, quad + 4);
            #pragma unroll
            for (int mi = 0; mi < 2; ++mi) {
                o[mi][nb] = __builtin_amdgcn_mfma_f32_16x16x32_bf16(pf[mi][0], va, o[mi][nb], 0, 0, 0);
                o[mi][nb] = __builtin_amdgcn_mfma_f32_16x16x32_bf16(pf[mi][1], vc, o[mi][nb], 0, 0, 0);
            }
        }
    }

    // ---- normalize + store O bf16 [b][n][h*64] ----
    const int b = bh >> 4, h = bh & 15;
    #pragma unroll
    for (int mi = 0; mi < 2; ++mi)
        #pragma unroll
        for (int r = 0; r < 4; ++r) {
            const int ig = rb0 + mi*16 + quad*4 + r;
            const float inv = 1.f / lacc[mi][r];
            ushort* op = Ob + ((size_t)(b * 2048 + ig)) * 1024 + h * 64 + l15;
            #pragma unroll
            for (int nb = 0; nb < 4; ++nb)
                op[nb * 16] = f2bf(o[mi][nb][r] * inv);
        }
}

// ---------------------------------------------------------------------------
extern "C" void kernel_launch(void* const* d_in, const int* in_sizes, int n_in,
                              void* d_out, int out_size, void* d_ws, size_t ws_size,
                              hipStream_t stream) {
    const float* x   = (const float*)d_in[0];
    const float* Wq  = (const float*)d_in[1];
    const float* Wkv = (const float*)d_in[2];
    const float* Wo  = (const float*)d_in[3];
    const float* bo  = (const float*)d_in[4];
    float* out = (float*)d_out;

    const size_t SEG = (size_t)8388608 * 2;   // 16 MB per bf16 [8192x1024]
    char* ws = (char*)d_ws;
    ushort* xb = (ushort*)(ws);
    ushort* Qb = (ushort*)(ws + SEG);
    ushort* Kb = (ushort*)(ws + SEG * 2);
    ushort* Vt = (ushort*)(ws + SEG * 3);     // [bh*64+d][2048]
    ushort* Ob = (ushort*)(ws + SEG * 4);
    ushort* Wt = (ushort*)(ws + SEG * 5);     // [4096][1024] bf16

    convert_x<<<dim3(4096), 256, 0, stream>>>(x, xb);
    prep_w<<<dim3(256), 256, 0, stream>>>(Wq, Wkv, Wo, Wt);
    gemm_qkv<<<dim3(12, 64), 512, 0, stream>>>(xb, Wt, Qb, Kb, Vt);
    flash_mfma<<<dim3(1024), 256, 0, stream>>>(Qb, Kb, Vt, Ob);
    gemm_out<<<dim3(4, 64), 512, 0, stream>>>(Ob, Wt + (size_t)3072 * 1024, bo, out);
}

// Round 5
// 258.140 us; speedup vs baseline: 1.0038x; 1.0038x over previous
//
#include <hip/hip_runtime.h>
#include <hip/hip_bf16.h>
#include <math.h>

typedef __attribute__((ext_vector_type(8))) short bf16x8;
typedef __attribute__((ext_vector_type(4))) float f32x4;

static __device__ inline ushort f2bf(float f) {
    union { float f; unsigned u; } v; v.f = f;
    unsigned r = (v.u + 0x7fff + ((v.u >> 16) & 1)) >> 16;   // RNE
    return (ushort)r;
}

#define GLD_LDS(g, l) \
    __builtin_amdgcn_global_load_lds( \
        (const __attribute__((address_space(1))) void*)(g), \
        (__attribute__((address_space(3))) void*)(l), 16, 0, 0)

#define MFMA_BF16(a, b, c) __builtin_amdgcn_mfma_f32_16x16x32_bf16((a), (b), (c), 0, 0, 0)

// ---------------------------------------------------------------------------
// x fp32 -> bf16
// ---------------------------------------------------------------------------
__global__ __launch_bounds__(256) void convert_x(
    const float* __restrict__ x, ushort* __restrict__ xb)
{
    const size_t i = ((size_t)blockIdx.x * 256 + threadIdx.x) * 8;
    float4 a = *(const float4*)(x + i);
    float4 b = *(const float4*)(x + i + 4);
    bf16x8 t;
    t[0] = (short)f2bf(a.x); t[1] = (short)f2bf(a.y);
    t[2] = (short)f2bf(a.z); t[3] = (short)f2bf(a.w);
    t[4] = (short)f2bf(b.x); t[5] = (short)f2bf(b.y);
    t[6] = (short)f2bf(b.z); t[7] = (short)f2bf(b.w);
    *(bf16x8*)(xb + i) = t;
}

// ---------------------------------------------------------------------------
// Weights fp32 [K][N] -> Wt bf16 [4096][1024] transposed
// ---------------------------------------------------------------------------
__global__ __launch_bounds__(256) void prep_w(
    const float* __restrict__ Wq, const float* __restrict__ Wkv,
    const float* __restrict__ Wo, ushort* __restrict__ Wt)
{
    const int w = threadIdx.x >> 6;
    const int lane = threadIdx.x & 63;
    const int tile = blockIdx.x * 4 + w;
    const int r0 = (tile >> 4) << 6;
    const int k0 = (tile & 15) << 6;

    const float* src; int ld, c0;
    if (r0 < 1024)      { src = Wq;  ld = 1024; c0 = r0; }
    else if (r0 < 3072) { src = Wkv; ld = 2048; c0 = r0 - 1024; }
    else                { src = Wo;  ld = 1024; c0 = r0 - 3072; }

    ushort v[64];
    #pragma unroll
    for (int k = 0; k < 64; ++k)
        v[k] = f2bf(src[(size_t)(k0 + k) * ld + c0 + lane]);

    ushort* dst = Wt + (size_t)(r0 + lane) * 1024 + k0;
    #pragma unroll
    for (int k = 0; k < 64; k += 8) {
        bf16x8 t;
        #pragma unroll
        for (int j = 0; j < 8; ++j) t[j] = (short)v[k + j];
        *(bf16x8*)(dst + k) = t;
    }
}

// ---------------------------------------------------------------------------
// gemm_qkv: m201-style 256x256 tile, BK=64, 512 thr / 8 waves (2M x 4N),
// per-wave output 128x64 (row-stripes: stripe0 = A-half0 rows wm*64..+63,
// stripe1 = A-half1 rows wm*64..+63). 4 phases per K-tile, 16 MFMA each.
// LDS 128 KB: [buf:2][half:2][128 rows][64 bf16] per operand.
//
// Phase schedule (per K-tile t; buf cur = t&1):
//  ph1: ds_read 8 B-frags (held whole tile) + A stripe0 rows 0-31;
//       stage (t+1):B1 -> buf cur^1 [no WAR: other buffer].
//  ph2: ds_read A stripe0 rows 32-63; stage (t+2):B0 -> cur
//       [WAR-safe: ALL B reads completed in ph1, ph1-closing barrier passed].
//  ph3: ds_read A stripe1 (all 8 frags); stage (t+2):A0 -> cur
//       [A0 reads = stripe0 = done by ph2-closing barrier].
//  ph4: no reads (stripe1 rows 32-63 in regs from ph3); stage (t+2):A1 -> cur
//       [A1 reads all in ph3, barrier passed]; vmcnt(6) (t<14) keeps the
//       3 newest half-tiles (t+2: B0,A0,A1) in flight; vmcnt(0) at t=14.
// Prologue: t0 all 4 halves (8 loads), vmcnt(4), t1 B0/A0/A1 (6), vmcnt(6).
// Swizzle: full 3-bit chunk ^= row&7 applied on the GLOBAL source (gload_lds
// writes linearly) and on the read side (r&7 == l15&7) -> 0 bank conflicts.
// K-accumulation order identical to previous rounds (ascending 32-chunks).
// ---------------------------------------------------------------------------
#define STG_A256(t, h) { \
    ushort* d_ = As2 + ((t) & 1) * 16384 + (h) * 8192 + tid * 8; \
    GLD_LDS(aG + (size_t)((h) * 128) * 1024 + (size_t)(t) * 64, d_); \
    GLD_LDS(aG + (size_t)((h) * 128 + 64) * 1024 + (size_t)(t) * 64, d_ + 4096); }
#define STG_B256(t, h) { \
    ushort* d_ = Bs2 + ((t) & 1) * 16384 + (h) * 8192 + tid * 8; \
    GLD_LDS(bG + (size_t)((h) * 128) * 1024 + (size_t)(t) * 64, d_); \
    GLD_LDS(bG + (size_t)((h) * 128 + 64) * 1024 + (size_t)(t) * 64, d_ + 4096); }

__global__ __launch_bounds__(512, 2) void gemm_qkv(
    const ushort* __restrict__ A, const ushort* __restrict__ Bt,
    ushort* __restrict__ Qb, ushort* __restrict__ Kb, ushort* __restrict__ Vt)
{
    __shared__ ushort As2[2 * 2 * 8192];   // 64 KB
    __shared__ ushort Bs2[2 * 2 * 8192];   // 64 KB

    const int tid = threadIdx.x;
    const int lane = tid & 63;
    const int w = tid >> 6;
    const int l15 = lane & 15;
    const int quad = lane >> 4;
    const int wm = w >> 2, wn = w & 3;                 // 2M x 4N waves

    const int lin = blockIdx.y * 12 + blockIdx.x;      // 384 blocks, %8==0
    const int wg = (lin & 7) * 48 + (lin >> 3);        // XCD-chunked bijection
    const int rowBase = (wg / 12) * 256;
    const int colBase = (wg % 12) * 256;

    // staging map: thread -> (row = tid>>3 [+64 for 2nd load], chunk = tid&7)
    const int srow = tid >> 3;
    const int gsw = ((tid & 7) ^ (srow & 7)) << 3;     // pre-swizzled src chunk
    const ushort* aG = A  + (size_t)(rowBase + srow) * 1024 + gsw;
    const ushort* bG = Bt + (size_t)(colBase + srow) * 1024 + gsw;

    // read-side swizzled chunk offsets (row&7 == l15&7 for all frag rows)
    const int c0 = (quad ^ (l15 & 7)) << 3;
    const int c1 = c0 ^ 32;

    f32x4 acc[8][4];
    #pragma unroll
    for (int i_ = 0; i_ < 8; ++i_)
        #pragma unroll
        for (int j_ = 0; j_ < 4; ++j_) acc[i_][j_] = (f32x4){0.f, 0.f, 0.f, 0.f};

    // ---- prologue ----
    STG_A256(0, 0) STG_A256(0, 1) STG_B256(0, 0) STG_B256(0, 1)
    asm volatile("s_waitcnt vmcnt(4)" ::: "memory");
    STG_B256(1, 0) STG_A256(1, 0) STG_A256(1, 1)
    asm volatile("s_waitcnt vmcnt(6)" ::: "memory");
    __builtin_amdgcn_s_barrier();
    asm volatile("" ::: "memory");

    #pragma unroll 1
    for (int t = 0; t < 16; ++t) {
        const int cur = t & 1;
        const ushort* Ar = As2 + cur * 16384;
        const ushort* Br = Bs2 + cur * 16384;
        const ushort* a0p = Ar + (wm * 64 + l15) * 64;          // stripe0 (A-half0)
        const ushort* a1p = a0p + 8192;                         // stripe1 (A-half1)
        const ushort* bp  = Br + (wn >> 1) * 8192 + ((wn & 1) * 64 + l15) * 64;

        // ---------------- phase 1 ----------------
        bf16x8 b0[4], b1[4];
        #pragma unroll
        for (int ni = 0; ni < 4; ++ni) {
            b0[ni] = *(const bf16x8*)(bp + ni * 1024 + c0);
            b1[ni] = *(const bf16x8*)(bp + ni * 1024 + c1);
        }
        bf16x8 aE0 = *(const bf16x8*)(a0p + c0);
        bf16x8 aO0 = *(const bf16x8*)(a0p + c1);
        bf16x8 aE1 = *(const bf16x8*)(a0p + 1024 + c0);
        bf16x8 aO1 = *(const bf16x8*)(a0p + 1024 + c1);
        if (t + 1 < 16) { STG_B256(t + 1, 1) }
        __builtin_amdgcn_s_barrier();
        asm volatile("s_waitcnt lgkmcnt(0)" ::: "memory");
        __builtin_amdgcn_sched_barrier(0);
        __builtin_amdgcn_s_setprio(1);
        #pragma unroll
        for (int ni = 0; ni < 4; ++ni) {
            acc[0][ni] = MFMA_BF16(aE0, b0[ni], acc[0][ni]);
            acc[0][ni] = MFMA_BF16(aO0, b1[ni], acc[0][ni]);
        }
        #pragma unroll
        for (int ni = 0; ni < 4; ++ni) {
            acc[1][ni] = MFMA_BF16(aE1, b0[ni], acc[1][ni]);
            acc[1][ni] = MFMA_BF16(aO1, b1[ni], acc[1][ni]);
        }
        __builtin_amdgcn_s_setprio(0);
        __builtin_amdgcn_s_barrier();
        asm volatile("" ::: "memory");

        // ---------------- phase 2 ----------------
        bf16x8 aE2 = *(const bf16x8*)(a0p + 2048 + c0);
        bf16x8 aO2 = *(const bf16x8*)(a0p + 2048 + c1);
        bf16x8 aE3 = *(const bf16x8*)(a0p + 3072 + c0);
        bf16x8 aO3 = *(const bf16x8*)(a0p + 3072 + c1);
        if (t + 2 < 16) { STG_B256(t + 2, 0) }
        __builtin_amdgcn_s_barrier();
        asm volatile("s_waitcnt lgkmcnt(0)" ::: "memory");
        __builtin_amdgcn_sched_barrier(0);
        __builtin_amdgcn_s_setprio(1);
        #pragma unroll
        for (int ni = 0; ni < 4; ++ni) {
            acc[2][ni] = MFMA_BF16(aE2, b0[ni], acc[2][ni]);
            acc[2][ni] = MFMA_BF16(aO2, b1[ni], acc[2][ni]);
        }
        #pragma unroll
        for (int ni = 0; ni < 4; ++ni) {
            acc[3][ni] = MFMA_BF16(aE3, b0[ni], acc[3][ni]);
            acc[3][ni] = MFMA_BF16(aO3, b1[ni], acc[3][ni]);
        }
        __builtin_amdgcn_s_setprio(0);
        __builtin_amdgcn_s_barrier();
        asm volatile("" ::: "memory");

        // ---------------- phase 3 ----------------
        bf16x8 s1E[4], s1O[4];
        #pragma unroll
        for (int rf = 0; rf < 4; ++rf) {
            s1E[rf] = *(const bf16x8*)(a1p + rf * 1024 + c0);
            s1O[rf] = *(const bf16x8*)(a1p + rf * 1024 + c1);
        }
        if (t + 2 < 16) { STG_A256(t + 2, 0) }
        __builtin_amdgcn_s_barrier();
        asm volatile("s_waitcnt lgkmcnt(0)" ::: "memory");
        __builtin_amdgcn_sched_barrier(0);
        __builtin_amdgcn_s_setprio(1);
        #pragma unroll
        for (int ni = 0; ni < 4; ++ni) {
            acc[4][ni] = MFMA_BF16(s1E[0], b0[ni], acc[4][ni]);
            acc[4][ni] = MFMA_BF16(s1O[0], b1[ni], acc[4][ni]);
        }
        #pragma unroll
        for (int ni = 0; ni < 4; ++ni) {
            acc[5][ni] = MFMA_BF16(s1E[1], b0[ni], acc[5][ni]);
            acc[5][ni] = MFMA_BF16(s1O[1], b1[ni], acc[5][ni]);
        }
        __builtin_amdgcn_s_setprio(0);
        __builtin_amdgcn_s_barrier();
        asm volatile("" ::: "memory");

        // ---------------- phase 4 ----------------
        if (t + 2 < 16) { STG_A256(t + 2, 1) }
        __builtin_amdgcn_s_barrier();
        __builtin_amdgcn_sched_barrier(0);
        __builtin_amdgcn_s_setprio(1);
        #pragma unroll
        for (int ni = 0; ni < 4; ++ni) {
            acc[6][ni] = MFMA_BF16(s1E[2], b0[ni], acc[6][ni]);
            acc[6][ni] = MFMA_BF16(s1O[2], b1[ni], acc[6][ni]);
        }
        #pragma unroll
        for (int ni = 0; ni < 4; ++ni) {
            acc[7][ni] = MFMA_BF16(s1E[3], b0[ni], acc[7][ni]);
            acc[7][ni] = MFMA_BF16(s1O[3], b1[ni], acc[7][ni]);
        }
        __builtin_amdgcn_s_setprio(0);
        if (t < 14)       { asm volatile("s_waitcnt vmcnt(6)" ::: "memory"); }
        else if (t == 14) { asm volatile("s_waitcnt vmcnt(0)" ::: "memory"); }
        if (t < 15) {
            __builtin_amdgcn_s_barrier();
            asm volatile("" ::: "memory");
        }
    }

    // ---- epilogue: seg-routed store ----
    const int seg = colBase >> 10;          // 0=Q 1=K 2=V (256-tiles don't straddle)
    if (seg == 2) {
        #pragma unroll
        for (int ri = 0; ri < 8; ++ri) {
            #pragma unroll
            for (int ni = 0; ni < 4; ++ni) {
                const int c = (colBase + wn*64 + ni*16 + l15) & 1023;
                const int h = c >> 6, d = c & 63;
                const int m = rowBase + ((ri >> 2) << 7) + wm*64 + (ri & 3)*16 + quad*4;
                const int b = m >> 11, nn = m & 2047;
                ushort4 v;
                v.x = f2bf(acc[ri][ni][0]); v.y = f2bf(acc[ri][ni][1]);
                v.z = f2bf(acc[ri][ni][2]); v.w = f2bf(acc[ri][ni][3]);
                *(ushort4*)(Vt + ((size_t)(b*16 + h)*64 + d)*2048 + nn) = v;
            }
        }
    } else {
        ushort* dst = seg ? Kb : Qb;
        // Q pre-scale: 1/sqrt(64) * log2(e)  (softmax runs in base-2 domain)
        const float sc2 = seg ? 1.0f : 0.18033688011112042f;
        #pragma unroll
        for (int ri = 0; ri < 8; ++ri) {
            #pragma unroll
            for (int ni = 0; ni < 4; ++ni) {
                const int c = (colBase + wn*64 + ni*16 + l15) & 1023;
                const int h = c >> 6, d = c & 63;
                #pragma unroll
                for (int r = 0; r < 4; ++r) {
                    const int m = rowBase + ((ri >> 2) << 7) + wm*64 + (ri & 3)*16 + quad*4 + r;
                    const int b = m >> 11, nn = m & 2047;
                    dst[((((size_t)b*16 + h)*2048 + nn) << 6) + d] = f2bf(acc[ri][ni][r] * sc2);
                }
            }
        }
    }
}

// ---------------------------------------------------------------------------
// gemm_out keeps the R4 tri-buffered 128x256 pipe (grid 256 = exact round).
// ---------------------------------------------------------------------------
#define STG32(t, Ad, Bd) { \
    GLD_LDS(aS + (size_t)(t) * 32, (Ad) + ldst); \
    GLD_LDS(bSlo + (size_t)(t) * 32, (Bd) + ldst); \
    GLD_LDS(bShi + (size_t)(t) * 32, (Bd) + 128 * 32 + ldst); }

#define GEMM_PIPE(Aptr, Btptr, NXT, NWG)                                       \
    __shared__ ushort As[3][128 * 32];                                         \
    __shared__ ushort Bs[3][256 * 32];                                         \
    const int tid = threadIdx.x;                                               \
    const int lane = tid & 63;                                                 \
    const int w = tid >> 6;                                                    \
    const int l15 = lane & 15;                                                 \
    const int quad = lane >> 4;                                                \
    const int wm = w >> 2, wn = w & 3;                                         \
    const int lin = blockIdx.y * (NXT) + blockIdx.x;                           \
    const int wg = (lin & 7) * ((NWG) >> 3) + (lin >> 3);                      \
    const int rowBase = (wg / (NXT)) * 128;                                    \
    const int colBase = (wg % (NXT)) * 256;                                    \
    const int sr = tid >> 2, sc = tid & 3;                                     \
    const int ldst = sr * 32 + sc * 8;                                         \
    const int gsw = (sc ^ ((sr >> 1) & 3)) << 3;                               \
    const ushort* aS   = (Aptr)  + (size_t)(rowBase + sr) * 1024 + gsw;        \
    const ushort* bSlo = (Btptr) + (size_t)(colBase + sr) * 1024 + gsw;        \
    const ushort* bShi = bSlo + (size_t)128 * 1024;                            \
    const int co = ((quad ^ ((l15 >> 1) & 3)) << 3);                           \
    f32x4 acc[4][4];                                                           \
    _Pragma("unroll")                                                          \
    for (int i_ = 0; i_ < 4; ++i_)                                             \
        _Pragma("unroll")                                                      \
        for (int j_ = 0; j_ < 4; ++j_) acc[i_][j_] = (f32x4){0.f, 0.f, 0.f, 0.f}; \
    ushort *Acur = As[0], *Anxt = As[1], *Apre = As[2];                        \
    ushort *Bcur = Bs[0], *Bnxt = Bs[1], *Bpre = Bs[2];                        \
    STG32(0, Acur, Bcur)                                                       \
    STG32(1, Anxt, Bnxt)                                                       \
    asm volatile("s_waitcnt vmcnt(3)" ::: "memory");                           \
    __builtin_amdgcn_s_barrier();                                              \
    asm volatile("" ::: "memory");                                             \
    _Pragma("unroll 1")                                                        \
    for (int u = 0; u < 32; ++u) {                                             \
        if (u + 2 < 32) { STG32(u + 2, Apre, Bpre) }                           \
        const ushort* aC = Acur + (wm * 64 + l15) * 32;                        \
        const ushort* bC = Bcur + (wn * 64 + l15) * 32;                        \
        bf16x8 aF[4], bF[4];                                                   \
        _Pragma("unroll")                                                      \
        for (int ni = 0; ni < 4; ++ni)                                         \
            bF[ni] = *(const bf16x8*)(bC + ni * 512 + co);                     \
        _Pragma("unroll")                                                      \
        for (int mi = 0; mi < 4; ++mi)                                         \
            aF[mi] = *(const bf16x8*)(aC + mi * 512 + co);                     \
        __builtin_amdgcn_s_setprio(1);                                         \
        _Pragma("unroll")                                                      \
        for (int mi = 0; mi < 4; ++mi)                                         \
            _Pragma("unroll")                                                  \
            for (int ni = 0; ni < 4; ++ni)                                     \
                acc[mi][ni] = __builtin_amdgcn_mfma_f32_16x16x32_bf16(         \
                    aF[mi], bF[ni], acc[mi][ni], 0, 0, 0);                     \
        __builtin_amdgcn_s_setprio(0);                                         \
        if (u < 30)       { asm volatile("s_waitcnt vmcnt(3)" ::: "memory"); } \
        else if (u == 30) { asm volatile("s_waitcnt vmcnt(0)" ::: "memory"); } \
        if (u < 31) {                                                          \
            __builtin_amdgcn_s_barrier();                                      \
            asm volatile("" ::: "memory");                                     \
        }                                                                      \
        ushort* tA = Acur; Acur = Anxt; Anxt = Apre; Apre = tA;                \
        ushort* tB = Bcur; Bcur = Bnxt; Bnxt = Bpre; Bpre = tB;                \
    }

__global__ __launch_bounds__(512, 4) void gemm_out(
    const ushort* __restrict__ A, const ushort* __restrict__ Bt,
    const float* __restrict__ bo, float* __restrict__ out)
{
    GEMM_PIPE(A, Bt, 4, 256)

    #pragma unroll
    for (int mi = 0; mi < 4; ++mi) {
        #pragma unroll
        for (int ni = 0; ni < 4; ++ni) {
            const int n = colBase + wn*64 + ni*16 + l15;
            const float bb = bo[n];
            #pragma unroll
            for (int r = 0; r < 4; ++r) {
                const int m = rowBase + wm*64 + mi*16 + quad*4 + r;
                out[(size_t)m * 1024 + n] = acc[mi][ni][r] + bb;
            }
        }
    }
}

// ---------------------------------------------------------------------------
// Flash attention v5: unpaired q-tiles (grid 1024, qt-descending dispatch),
// double-buffered LDS K/V, S^T trick, skip-rescale on no-new-max.
// Block = 4 waves x 32 q-rows = one 128-row q-tile.
// ---------------------------------------------------------------------------
__device__ __forceinline__ bf16x8 lds_frag(const ushort* S, int row, int chunk) {
    return *(const bf16x8*)(S + row * 64 + ((chunk ^ (row & 7)) << 3));
}

__global__ __launch_bounds__(256, 2) void flash_mfma(
    const ushort* __restrict__ Qb,
    const ushort* __restrict__ Kb,
    const ushort* __restrict__ Vt,
    ushort* __restrict__ Ob)
{
    __shared__ ushort Ks[2][4096];
    __shared__ ushort Vs[2][4096];
    __shared__ ushort PsAll[4][32][72];

    const int tid = threadIdx.x;
    const int w = tid >> 6;
    const int lane = tid & 63;
    const int l15 = lane & 15;
    const int quad = lane >> 4;
    ushort (*Ps)[72] = PsAll[w];

    const int blk = blockIdx.x;
    const int bh = ((blk & 7) << 3) | ((blk >> 3) & 7);
    const int qt = 15 - (blk >> 6);
    const int nt = 2 * qt + 2;
    const int rb0 = (qt << 7) + w * 32;

    const int sr0 = tid >> 3, sr1 = sr0 + 32;
    const int cg0 = (tid & 7) ^ (sr0 & 7);
    const int cg1 = (tid & 7) ^ (sr1 & 7);
    const ushort* kgb = Kb + (size_t)bh * 131072;
    const ushort* vgb = Vt + (size_t)bh * 131072;

    bf16x8 qf[2][2];
    #pragma unroll
    for (int mi = 0; mi < 2; ++mi) {
        const ushort* qp = Qb + ((size_t)bh * 2048 + rb0 + mi*16 + l15) * 64 + quad * 8;
        qf[mi][0] = *(const bf16x8*)qp;
        qf[mi][1] = *(const bf16x8*)(qp + 32);
    }

    bf16x8 bones;
    #pragma unroll
    for (int j = 0; j < 8; ++j) bones[j] = (short)0x3F80;   // bf16 1.0

    float m_r[2];
    f32x4 o[2][4], lacc[2];
    #pragma unroll
    for (int mi = 0; mi < 2; ++mi) {
        m_r[mi] = -INFINITY;
        lacc[mi] = (f32x4){0.f, 0.f, 0.f, 0.f};
        #pragma unroll
        for (int nb = 0; nb < 4; ++nb) o[mi][nb] = (f32x4){0.f, 0.f, 0.f, 0.f};
    }

    GLD_LDS(kgb + sr0*64 + cg0*8, &Ks[0][tid*8]);
    GLD_LDS(kgb + sr1*64 + cg1*8, &Ks[0][tid*8 + 2048]);
    GLD_LDS(vgb + (size_t)sr0*2048 + cg0*8, &Vs[0][tid*8]);
    GLD_LDS(vgb + (size_t)sr1*2048 + cg1*8, &Vs[0][tid*8 + 2048]);

    for (int t = 0; t < nt; ++t) {
        __syncthreads();
        const int cur = t & 1;
        if (t + 1 < nt) {
            const int jn = t + 1;
            ushort* kd = &Ks[cur ^ 1][tid * 8];
            ushort* vd = &Vs[cur ^ 1][tid * 8];
            GLD_LDS(kgb + (size_t)jn*4096 + sr0*64 + cg0*8, kd);
            GLD_LDS(kgb + (size_t)jn*4096 + sr1*64 + cg1*8, kd + 2048);
            GLD_LDS(vgb + (size_t)sr0*2048 + jn*64 + cg0*8, vd);
            GLD_LDS(vgb + (size_t)sr1*2048 + jn*64 + cg1*8, vd + 2048);
        }
        const int j0 = t << 6;
        if (j0 > rb0 + 31) continue;

        const ushort* Ksb = Ks[cur];
        const ushort* Vsb = Vs[cur];

        f32x4 St[2][4];
        #pragma unroll
        for (int kb = 0; kb < 4; ++kb) {
            bf16x8 ka = lds_frag(Ksb, kb*16 + l15, quad);
            bf16x8 kc = lds_frag(Ksb, kb*16 + l15, quad + 4);
            #pragma unroll
            for (int mi = 0; mi < 2; ++mi) {
                f32x4 s = (f32x4){0.f, 0.f, 0.f, 0.f};
                s = MFMA_BF16(ka, qf[mi][0], s);
                s = MFMA_BF16(kc, qf[mi][1], s);
                St[mi][kb] = s;
            }
        }

        #pragma unroll
        for (int mi = 0; mi < 2; ++mi) {
            const int qrow = rb0 + mi*16 + l15;
            if (j0 + 63 > rb0 + mi*16) {
                #pragma unroll
                for (int kb = 0; kb < 4; ++kb) {
                    const int kbase = j0 + kb*16 + quad*4;
                    #pragma unroll
                    for (int r = 0; r < 4; ++r)
                        if (kbase + r > qrow) St[mi][kb][r] = -INFINITY;
                }
            }
            f32x4 mv = St[mi][0];
            #pragma unroll
            for (int kb = 1; kb < 4; ++kb)
                #pragma unroll
                for (int r = 0; r < 4; ++r) mv[r] = fmaxf(mv[r], St[mi][kb][r]);
            float mx = fmaxf(fmaxf(mv[0], mv[1]), fmaxf(mv[2], mv[3]));
            mx = fmaxf(mx, __shfl_xor(mx, 16));
            mx = fmaxf(mx, __shfl_xor(mx, 32));
            const float mold = m_r[mi];
            const float mnew = fmaxf(mold, mx);
            if (__any(mnew > mold)) {
                m_r[mi] = mnew;
                const float corr = __builtin_amdgcn_exp2f(mold - mnew);
                float ct[4];
                #pragma unroll
                for (int r = 0; r < 4; ++r) ct[r] = __shfl(corr, quad*4 + r);
                #pragma unroll
                for (int r = 0; r < 4; ++r) lacc[mi][r] *= ct[r];
                #pragma unroll
                for (int nb = 0; nb < 4; ++nb)
                    #pragma unroll
                    for (int r = 0; r < 4; ++r) o[mi][nb][r] *= ct[r];
            }
            #pragma unroll
            for (int kb = 0; kb < 4; ++kb)
                #pragma unroll
                for (int r = 0; r < 4; ++r)
                    St[mi][kb][r] = __builtin_amdgcn_exp2f(St[mi][kb][r] - mnew);
            #pragma unroll
            for (int kb = 0; kb < 4; ++kb) {
                union { float f; unsigned u; } c0_, c1_, c2_, c3_;
                c0_.f = St[mi][kb][0]; c1_.f = St[mi][kb][1];
                c2_.f = St[mi][kb][2]; c3_.f = St[mi][kb][3];
                uint2 pk;
                pk.x = (c0_.u >> 16) | (c1_.u & 0xFFFF0000u);
                pk.y = (c2_.u >> 16) | (c3_.u & 0xFFFF0000u);
                *(uint2*)&Ps[mi*16 + l15][kb*16 + quad*4] = pk;
            }
        }

        bf16x8 pf[2][2];
        #pragma unroll
        for (int mi = 0; mi < 2; ++mi) {
            pf[mi][0] = *(const bf16x8*)&Ps[mi*16 + l15][quad * 8];
            pf[mi][1] = *(const bf16x8*)&Ps[mi*16 + l15][32 + quad * 8];
        }
        #pragma unroll
        for (int mi = 0; mi < 2; ++mi) {
            lacc[mi] = MFMA_BF16(pf[mi][0], bones, lacc[mi]);
            lacc[mi] = MFMA_BF16(pf[mi][1], bones, lacc[mi]);
        }
        #pragma unroll
        for (int nb = 0; nb < 4; ++nb) {
            bf16x8 va = lds_frag(Vsb, nb*16 + l15, quad);
            bf16x8 vc = lds_frag(Vsb, nb*16 + l15, quad + 4);
            #pragma unroll
            for (int mi = 0; mi < 2; ++mi) {
                o[mi][nb] = MFMA_BF16(pf[mi][0], va, o[mi][nb]);
                o[mi][nb] = MFMA_BF16(pf[mi][1], vc, o[mi][nb]);
            }
        }
    }

    const int b = bh >> 4, h = bh & 15;
    #pragma unroll
    for (int mi = 0; mi < 2; ++mi)
        #pragma unroll
        for (int r = 0; r < 4; ++r) {
            const int ig = rb0 + mi*16 + quad*4 + r;
            const float inv = 1.f / lacc[mi][r];
            ushort* op = Ob + ((size_t)(b * 2048 + ig)) * 1024 + h * 64 + l15;
            #pragma unroll
            for (int nb = 0; nb < 4; ++nb)
                op[nb * 16] = f2bf(o[mi][nb][r] * inv);
        }
}

// ---------------------------------------------------------------------------
extern "C" void kernel_launch(void* const* d_in, const int* in_sizes, int n_in,
                              void* d_out, int out_size, void* d_ws, size_t ws_size,
                              hipStream_t stream) {
    const float* x   = (const float*)d_in[0];
    const float* Wq  = (const float*)d_in[1];
    const float* Wkv = (const float*)d_in[2];
    const float* Wo  = (const float*)d_in[3];
    const float* bo  = (const float*)d_in[4];
    float* out = (float*)d_out;

    const size_t SEG = (size_t)8388608 * 2;   // 16 MB per bf16 [8192x1024]
    char* ws = (char*)d_ws;
    ushort* xb = (ushort*)(ws);
    ushort* Qb = (ushort*)(ws + SEG);
    ushort* Kb = (ushort*)(ws + SEG * 2);
    ushort* Vt = (ushort*)(ws + SEG * 3);     // [bh*64+d][2048]
    ushort* Ob = (ushort*)(ws + SEG * 4);
    ushort* Wt = (ushort*)(ws + SEG * 5);     // [4096][1024] bf16

    convert_x<<<dim3(4096), 256, 0, stream>>>(x, xb);
    prep_w<<<dim3(256), 256, 0, stream>>>(Wq, Wkv, Wo, Wt);
    gemm_qkv<<<dim3(12, 32), 512, 0, stream>>>(xb, Wt, Qb, Kb, Vt);
    flash_mfma<<<dim3(1024), 256, 0, stream>>>(Qb, Kb, Vt, Ob);
    gemm_out<<<dim3(4, 64), 512, 0, stream>>>(Ob, Wt + (size_t)3072 * 1024, bo, out);
}